// Round 2
// baseline (194.780 us; speedup 1.0000x reference)
//
#include <hip/hip_runtime.h>

// Problem constants (from reference)
#define VOCAB 50257
#define SEQ   2048
#define EMB   512
#define BATCH 8

// ---------------------------------------------------------------------------
// Transpose W_emb (EMB, VOCAB) -> WT (VOCAB, EMB).
// 64x64 tile, 256 threads (tx=0..15, ty=0..15), LDS padded to pitch 65.
//   Read : scalar dword loads, 16 contiguous lanes x 4B = 64B segments,
//          4 rows per wave instruction (VOCAB odd => rows only 4B-aligned,
//          so float4 reads would be misaligned).
//   Write: float4 stores along E; row start v*EMB*4 = v*2048B is 16B-aligned.
//          64 lanes x 16B = 1KB-ish contiguous per pair of v-rows.
// LDS bank aliasing is 2-way max on both phases (free on gfx950).
// ---------------------------------------------------------------------------
__global__ __launch_bounds__(256)
void transpose_k(const float* __restrict__ in, float* __restrict__ out) {
    __shared__ float tile[64][65];
    const int v0 = blockIdx.x * 64;
    const int e0 = blockIdx.y * 64;
    const int tx = threadIdx.x;   // 0..15
    const int ty = threadIdx.y;   // 0..15
    const bool full = (v0 + 64 <= VOCAB);

    if (full) {
#pragma unroll
        for (int j = 0; j < 4; ++j) {
            const int e_l = ty + 16 * j;
            const size_t row = (size_t)(e0 + e_l) * VOCAB + v0;
#pragma unroll
            for (int m = 0; m < 4; ++m) {
                tile[e_l][tx + 16 * m] = in[row + tx + 16 * m];
            }
        }
        __syncthreads();
#pragma unroll
        for (int j = 0; j < 4; ++j) {
            const int v_l = ty + 16 * j;
            float4 w;
            w.x = tile[4 * tx + 0][v_l];
            w.y = tile[4 * tx + 1][v_l];
            w.z = tile[4 * tx + 2][v_l];
            w.w = tile[4 * tx + 3][v_l];
            *(float4*)&out[(size_t)(v0 + v_l) * EMB + e0 + 4 * tx] = w;
        }
    } else {
        // Edge tile (last 17 vocab columns): guarded scalar path.
        for (int j = 0; j < 4; ++j) {
            const int e_l = ty + 16 * j;
            const size_t row = (size_t)(e0 + e_l) * VOCAB;
            for (int m = 0; m < 4; ++m) {
                const int v = v0 + tx + 16 * m;
                tile[e_l][tx + 16 * m] = (v < VOCAB) ? in[row + v] : 0.0f;
            }
        }
        __syncthreads();
        for (int j = 0; j < 4; ++j) {
            const int v_l = ty + 16 * j;
            const int v = v0 + v_l;
            if (v < VOCAB) {
                float4 w;
                w.x = tile[4 * tx + 0][v_l];
                w.y = tile[4 * tx + 1][v_l];
                w.z = tile[4 * tx + 2][v_l];
                w.w = tile[4 * tx + 3][v_l];
                *(float4*)&out[(size_t)v * EMB + e0 + 4 * tx] = w;
            }
        }
    }
}

__device__ __forceinline__ float4 f4add(float4 a, float4 b) {
    return make_float4(a.x + b.x, a.y + b.y, a.z + b.z, a.w + b.w);
}

// Coalesced gather from the transposed table + fused positional add.
// One thread per float4 of output. Per wave: 1KB contiguous read from the
// token's WT row, 1KB from W_pos row, 1KB write.
__global__ __launch_bounds__(256)
void gather_k(const int* __restrict__ tokens,
              const float4* __restrict__ WT,    // (VOCAB, EMB/4)
              const float4* __restrict__ Wpos,  // (SEQ, EMB/4)
              float4* __restrict__ out) {
    const int idx = blockIdx.x * blockDim.x + threadIdx.x;
    const int e4  = idx & (EMB / 4 - 1);    // 0..127
    const int ts  = idx >> 7;               // b*SEQ + s
    const int s   = ts & (SEQ - 1);
    const int t   = tokens[ts];
    const float4 emb = WT[(size_t)t * (EMB / 4) + e4];
    const float4 pos = Wpos[(size_t)s * (EMB / 4) + e4];
    out[idx] = f4add(emb, pos);
}

// Fallback if workspace can't hold the transposed table: direct strided gather.
__global__ __launch_bounds__(256)
void gather_direct_k(const int* __restrict__ tokens,
                     const float* __restrict__ W_emb,  // (EMB, VOCAB)
                     const float4* __restrict__ Wpos,
                     float4* __restrict__ out) {
    const int idx = blockIdx.x * blockDim.x + threadIdx.x;
    const int e4  = idx & (EMB / 4 - 1);
    const int ts  = idx >> 7;
    const int s   = ts & (SEQ - 1);
    const int t   = tokens[ts];
    const int e   = e4 * 4;
    float4 r;
    r.x = W_emb[(size_t)(e + 0) * VOCAB + t];
    r.y = W_emb[(size_t)(e + 1) * VOCAB + t];
    r.z = W_emb[(size_t)(e + 2) * VOCAB + t];
    r.w = W_emb[(size_t)(e + 3) * VOCAB + t];
    out[idx] = f4add(r, Wpos[(size_t)s * (EMB / 4) + e4]);
}

extern "C" void kernel_launch(void* const* d_in, const int* in_sizes, int n_in,
                              void* d_out, int out_size, void* d_ws, size_t ws_size,
                              hipStream_t stream) {
    const int*   tokens = (const int*)d_in[0];
    const float* W_emb  = (const float*)d_in[1];   // (EMB, VOCAB)
    const float* W_pos  = (const float*)d_in[2];   // (SEQ, EMB)
    float*       out    = (float*)d_out;           // (BATCH, SEQ, EMB)

    const size_t need = (size_t)VOCAB * EMB * sizeof(float);  // ~103 MB
    const int n_out4  = BATCH * SEQ * (EMB / 4);              // 2,097,152
    const int gblocks = n_out4 / 256;                          // 8192

    if (ws_size >= need) {
        float* WT = (float*)d_ws;
        dim3 tgrid((VOCAB + 63) / 64, EMB / 64);               // 786 x 8
        transpose_k<<<tgrid, dim3(16, 16), 0, stream>>>(W_emb, WT);
        gather_k<<<gblocks, 256, 0, stream>>>(tokens, (const float4*)WT,
                                              (const float4*)W_pos, (float4*)out);
    } else {
        gather_direct_k<<<gblocks, 256, 0, stream>>>(tokens, W_emb,
                                                     (const float4*)W_pos, (float4*)out);
    }
}